// Round 18
// baseline (75.341 us; speedup 1.0000x reference)
//
#include <hip/hip_runtime.h>
#include <hip/hip_bf16.h>
#include <cstdint>
#include <cstddef>

typedef short bf16x8 __attribute__((ext_vector_type(8)));
typedef float f32x4 __attribute__((ext_vector_type(4)));
typedef unsigned short u16x8 __attribute__((ext_vector_type(8)));

#define DEV __device__ __forceinline__

DEV void gload16(const void* g, void* l) {
  __builtin_amdgcn_global_load_lds((const __attribute__((address_space(1))) void*)g,
                                   (__attribute__((address_space(3))) void*)l,
                                   16, 0, 0);
}

DEV unsigned short f2bf(float f) {
  __hip_bfloat16 h = __float2bfloat16(f);
  return *reinterpret_cast<unsigned short*>(&h);
}

DEV float b2f(unsigned short u) {
  union { float f; unsigned int i; } v;
  v.i = ((unsigned int)u) << 16;
  return v.f;
}

// ---- prep: Wvt[d][k] = sum_h WqkvV ; Wst[m][d] = sum_h Wout. One kernel, role by bid ----
__global__ __launch_bounds__(256) void k_prep(const float* __restrict__ Wqkv,
                                              const float* __restrict__ Wout,
                                              unsigned short* __restrict__ Wvt,
                                              unsigned short* __restrict__ Wst) {
  const int bid = blockIdx.x, t = threadIdx.x;
  if (bid < 1024) {
    int gid = bid * 256 + t;  // 2048 k x 128 d
    int k = gid >> 7, d = gid & 127;
    const float* p = Wqkv + (size_t)k * 6144 + 256 + d;
    float s = 0.f;
#pragma unroll
    for (int h = 0; h < 16; ++h) s += __builtin_nontemporal_load(p + h * 384);
    Wvt[(size_t)d * 2048 + k] = f2bf(s);
  } else {
    int gid = (bid - 1024) * 256 + t;  // 128 d x 2048 m
    int d = gid >> 11, m = gid & 2047;
    const float* p = Wout + (size_t)d * 2048 + m;
    float s = 0.f;
#pragma unroll
    for (int h = 0; h < 16; ++h) s += __builtin_nontemporal_load(p + h * 262144);
    Wst[(size_t)m * 128 + d] = f2bf(s);
  }
}

// ---- beff[m] = bout[m] + sum_d (sum_h bqkv[h][256+d]) * Ws[d][m] ----
__global__ __launch_bounds__(256) void k_beff(const float* __restrict__ bqkv,
                                              const unsigned short* __restrict__ Wst,
                                              const float* __restrict__ bout,
                                              float* __restrict__ be) {
  __shared__ float bv[128];
  int t = threadIdx.x;
  if (t < 128) {
    float s = 0.f;
#pragma unroll
    for (int h = 0; h < 16; ++h) s += bqkv[h * 384 + 256 + t];
    bv[t] = s;
  }
  __syncthreads();
  int m = blockIdx.x * 256 + t;  // grid 8
  float s = bout[m];
  const unsigned short* wr = Wst + (size_t)m * 128;
  for (int d = 0; d < 128; ++d) s = fmaf(bv[d], b2f(wr[d]), s);
  be[m] = s;
}

// ---- GEMM1: T[16384][128] bf16 = X(fp32) * Wvt^T ----
// r18: m-tile 64, BK 64 -> 128 (16 K-tiles): barrier/vmcnt events per staged byte halve
// again — the lever behind every gemm1 win this session (r12->r16). r17 proved TLP is
// not the constraint (8 vs 16 waves/CU identical), so 1 block/CU is fine.
// Depth-2 double buffer, 2 x 64 KB = 128 KB dynamic LDS. Same proven issue order:
// STAGE(t+1) -> VMCNT(8) -> BAR -> COMPUTE(t) -> BAR.  8 gload16/thread/tile
// (4 x + 4 Wvt) -> VMCNT(8) = tile t resident, t+1 in flight.
// Swizzle rule #21 both-sides: x rows 512 B, Wvt rows 256 B (bank-aligned) -> (row&7)<<4.
__global__ __launch_bounds__(512, 2) void k_gemm1(const float* __restrict__ X,
                                                  const unsigned short* __restrict__ Wvt,
                                                  unsigned short* __restrict__ T) {
  extern __shared__ char smem[];  // 2 x (32 KB x + 32 KB Wvt)
  const int t = threadIdx.x, lane = t & 63, w = t >> 6;
  const int wm = w >> 1, wn = w & 1;
  const int l15 = lane & 15, l4 = lane >> 4;
  const int m0 = blockIdx.x * 64;

  // staging addresses (pre-swizzled source per rule #21; LDS dest wave-uniform base)
  int xrow_[4], xsrc_[4];
#pragma unroll
  for (int c = 0; c < 4; ++c) {
    xrow_[c] = c * 16 + (t >> 5);                  // 0..63 (x row, 512 B each)
    xsrc_[c] = ((t & 31) << 4) ^ ((xrow_[c] & 7) << 4);
  }
  int wrow_[4], wsrc_[4];
#pragma unroll
  for (int c = 0; c < 4; ++c) {
    wrow_[c] = c * 32 + (t >> 4);                  // 0..127 (Wvt row, 256 B each)
    wsrc_[c] = ((t & 15) << 4) ^ ((wrow_[c] & 7) << 4);
  }

  f32x4 acc[4];
#pragma unroll
  for (int ni = 0; ni < 4; ++ni)
#pragma unroll
    for (int r = 0; r < 4; ++r) acc[ni][r] = 0.f;

#define VMCNT(n) asm volatile("s_waitcnt vmcnt(" #n ")" ::: "memory")
#define BAR() __builtin_amdgcn_s_barrier()
#define SCHED0() __builtin_amdgcn_sched_barrier(0)

#define STAGE(tt, buf)                                                         \
  do {                                                                         \
    _Pragma("unroll") for (int c = 0; c < 4; ++c)                              \
        gload16((const char*)(X + (size_t)(m0 + xrow_[c]) * 2048) +            \
                    (tt) * 512 + xsrc_[c],                                     \
                smem + (buf) * 65536 + c * 8192 + w * 1024);                   \
    _Pragma("unroll") for (int c = 0; c < 4; ++c)                              \
        gload16((const char*)Wvt + (size_t)wrow_[c] * 4096 + (tt) * 256 +      \
                    wsrc_[c],                                                  \
                smem + (buf) * 65536 + 32768 + c * 8192 + w * 1024);           \
  } while (0)

#define COMPUTE(buf)                                                           \
  do {                                                                         \
    const char* xs = smem + (buf) * 65536;                                     \
    const char* ws = smem + (buf) * 65536 + 32768;                             \
    const int arow = wm * 16 + l15;                                            \
    const char* xr = xs + arow * 512;                                          \
    const int aswz = (arow & 7) << 4;                                          \
    _Pragma("unroll") for (int ks = 0; ks < 4; ++ks) {                         \
      f32x4 a0 = *(const f32x4*)(xr + ((ks * 128 + l4 * 32) ^ aswz));          \
      f32x4 a1 = *(const f32x4*)(xr + ((ks * 128 + l4 * 32 + 16) ^ aswz));     \
      u16x8 u;                                                                 \
      _Pragma("unroll") for (int jj = 0; jj < 4; ++jj) {                       \
        u[jj] = f2bf(a0[jj]); u[jj + 4] = f2bf(a1[jj]);                        \
      }                                                                        \
      bf16x8 af = (bf16x8)u;                                                   \
      _Pragma("unroll") for (int ni = 0; ni < 4; ++ni) {                       \
        const int brow = wn * 64 + ni * 16 + l15;                              \
        bf16x8 bf = *(const bf16x8*)(ws + brow * 256 +                         \
                                     ((ks * 64 + l4 * 16) ^ ((brow & 7) << 4)));\
        acc[ni] = __builtin_amdgcn_mfma_f32_16x16x32_bf16(af, bf,              \
                                                          acc[ni], 0, 0, 0);   \
      }                                                                        \
    }                                                                          \
  } while (0)

#define TILE(tt, bR, bS)                                                       \
  STAGE((tt) + 1, bS); VMCNT(8); BAR(); SCHED0();                              \
  COMPUTE(bR); SCHED0(); BAR();

  STAGE(0, 0);

#pragma unroll 1
  for (int it = 0; it < 7; ++it) {
    const int tb = it * 2;
    TILE(tb + 0, 0, 1)
    TILE(tb + 1, 1, 0)
  }
  TILE(14, 0, 1)
  // tail: tile 15 in buf1
  VMCNT(0); BAR(); SCHED0(); COMPUTE(1);

#undef TILE
#undef COMPUTE
#undef STAGE
#undef VMCNT
#undef BAR
#undef SCHED0

#pragma unroll
  for (int ni = 0; ni < 4; ++ni)
#pragma unroll
    for (int r = 0; r < 4; ++r) {
      int row = m0 + wm * 16 + l4 * 4 + r;
      int col = wn * 64 + ni * 16 + l15;
      T[(size_t)row * 128 + col] = f2bf(acc[ni][r]);
    }
}

// ---- GEMM2: Y[16384][2048] fp32 = T * Wst^T + beff.  K=128 single sweep ----
// r12 version (proven): grid (256 m, 16 n), 4 blocks/CU, B-tile 32 KB one-shot stage.
__global__ __launch_bounds__(256, 4) void k_gemm2(const unsigned short* __restrict__ Tm,
                                                  const unsigned short* __restrict__ Wst,
                                                  const float* __restrict__ be,
                                                  float* __restrict__ Y) {
  __shared__ char bs[32768];
  const int t = threadIdx.x, lane = t & 63, w = t >> 6;
  const int l15 = lane & 15, l4 = lane >> 4;
  const int m0 = blockIdx.x * 64, n0 = blockIdx.y * 128;

#pragma unroll
  for (int c = 0; c < 8; ++c) {
    int row = c * 16 + (t >> 4);
    int sc = ((t & 15) * 16) ^ ((row & 7) << 4);
    gload16((const char*)Wst + (size_t)(n0 + row) * 256 + sc, bs + c * 4096 + w * 1024);
  }
  const unsigned short* trow = Tm + (size_t)(m0 + w * 16 + l15) * 128;
  bf16x8 afr[4];
#pragma unroll
  for (int kq = 0; kq < 4; ++kq) afr[kq] = *(const bf16x8*)(trow + kq * 32 + l4 * 8);
  __syncthreads();

  f32x4 acc[8];
#pragma unroll
  for (int nf = 0; nf < 8; ++nf)
#pragma unroll
    for (int r = 0; r < 4; ++r) acc[nf][r] = 0.f;

#pragma unroll
  for (int nf = 0; nf < 8; ++nf) {
    int row = nf * 16 + l15;
#pragma unroll
    for (int kq = 0; kq < 4; ++kq) {
      int byt = (kq * 64 + l4 * 16) ^ ((row & 7) << 4);
      bf16x8 bf = *(const bf16x8*)(bs + row * 256 + byt);
      acc[nf] = __builtin_amdgcn_mfma_f32_16x16x32_bf16(afr[kq], bf, acc[nf], 0, 0, 0);
    }
  }

#pragma unroll
  for (int nf = 0; nf < 8; ++nf) {
    int n = n0 + nf * 16 + l15;
    float bv = be[n];
#pragma unroll
    for (int r = 0; r < 4; ++r) {
      int row = m0 + w * 16 + l4 * 4 + r;
      Y[(size_t)row * 2048 + n] = acc[nf][r] + bv;
    }
  }
}

extern "C" void kernel_launch(void* const* d_in, const int* in_sizes, int n_in,
                              void* d_out, int out_size, void* d_ws, size_t ws_size,
                              hipStream_t stream) {
  const float* x    = (const float*)d_in[0];
  const float* Wqkv = (const float*)d_in[1];
  const float* bqkv = (const float*)d_in[2];
  const float* Wout = (const float*)d_in[3];
  const float* bout = (const float*)d_in[4];
  float* y = (float*)d_out;

  char* ws = (char*)d_ws;
  unsigned short* Wvt  = (unsigned short*)(ws);             //   524,288 B  [128][2048] bf16
  unsigned short* Wst  = (unsigned short*)(ws + 524288);    //   524,288 B  [2048][128] bf16
  float*          beff = (float*)(ws + 1048576);            //     8,192 B
  unsigned short* T    = (unsigned short*)(ws + 1056768);   // 4,194,304 B  [16384][128] bf16

  k_prep<<<2048, 256, 0, stream>>>(Wqkv, Wout, Wvt, Wst);
  k_beff<<<8, 256, 0, stream>>>(bqkv, Wst, bout, beff);
  k_gemm1<<<256, 512, 131072, stream>>>(x, Wvt, T);
  k_gemm2<<<dim3(256, 16), 256, 0, stream>>>(T, Wst, beff, y);
}

// Round 19
// 71.841 us; speedup vs baseline: 1.0487x; 1.0487x over previous
//
#include <hip/hip_runtime.h>
#include <hip/hip_bf16.h>
#include <cstdint>
#include <cstddef>

typedef short bf16x8 __attribute__((ext_vector_type(8)));
typedef float f32x4 __attribute__((ext_vector_type(4)));
typedef unsigned short u16x8 __attribute__((ext_vector_type(8)));

#define DEV __device__ __forceinline__

DEV void gload16(const void* g, void* l) {
  __builtin_amdgcn_global_load_lds((const __attribute__((address_space(1))) void*)g,
                                   (__attribute__((address_space(3))) void*)l,
                                   16, 0, 0);
}

DEV unsigned short f2bf(float f) {
  __hip_bfloat16 h = __float2bfloat16(f);
  return *reinterpret_cast<unsigned short*>(&h);
}

DEV float b2f(unsigned short u) {
  union { float f; unsigned int i; } v;
  v.i = ((unsigned int)u) << 16;
  return v.f;
}

// ---- prep: Wvt[d][k] = sum_h WqkvV ; Wst[m][d] = sum_h Wout. One kernel, role by bid ----
__global__ __launch_bounds__(256) void k_prep(const float* __restrict__ Wqkv,
                                              const float* __restrict__ Wout,
                                              unsigned short* __restrict__ Wvt,
                                              unsigned short* __restrict__ Wst) {
  const int bid = blockIdx.x, t = threadIdx.x;
  if (bid < 1024) {
    int gid = bid * 256 + t;  // 2048 k x 128 d
    int k = gid >> 7, d = gid & 127;
    const float* p = Wqkv + (size_t)k * 6144 + 256 + d;
    float s = 0.f;
#pragma unroll
    for (int h = 0; h < 16; ++h) s += __builtin_nontemporal_load(p + h * 384);
    Wvt[(size_t)d * 2048 + k] = f2bf(s);
  } else {
    int gid = (bid - 1024) * 256 + t;  // 128 d x 2048 m
    int d = gid >> 11, m = gid & 2047;
    const float* p = Wout + (size_t)d * 2048 + m;
    float s = 0.f;
#pragma unroll
    for (int h = 0; h < 16; ++h) s += __builtin_nontemporal_load(p + h * 262144);
    Wst[(size_t)m * 128 + d] = f2bf(s);
  }
}

// ---- beff[m] = bout[m] + sum_d (sum_h bqkv[h][256+d]) * Ws[d][m] ----
__global__ __launch_bounds__(256) void k_beff(const float* __restrict__ bqkv,
                                              const unsigned short* __restrict__ Wst,
                                              const float* __restrict__ bout,
                                              float* __restrict__ be) {
  __shared__ float bv[128];
  int t = threadIdx.x;
  if (t < 128) {
    float s = 0.f;
#pragma unroll
    for (int h = 0; h < 16; ++h) s += bqkv[h * 384 + 256 + t];
    bv[t] = s;
  }
  __syncthreads();
  int m = blockIdx.x * 256 + t;  // grid 8
  float s = bout[m];
  const unsigned short* wr = Wst + (size_t)m * 128;
  for (int d = 0; d < 128; ++d) s = fmaf(bv[d], b2f(wr[d]), s);
  be[m] = s;
}

// ---- GEMM1: T[16384][128] bf16 = X(fp32) * Wvt^T ----
// r19 = r16 champion, reverted verbatim (best total 72.03 µs):
// m-tile 64, 256 blocks x 512 thr / 8 waves, depth-3 pipeline, 96 KB LDS, 1 block/CU.
// STAGE(t+2) -> VMCNT(8) -> BAR -> COMPUTE(t) -> BAR; 4 gload16/thread/tile.
// r17 (depth2, 2 blocks/CU) = 73.5, r18 (BK=128) = 75.3 — both within/behind; this
// configuration is the measured optimum of the ladder.
__global__ __launch_bounds__(512, 1) void k_gemm1(const float* __restrict__ X,
                                                  const unsigned short* __restrict__ Wvt,
                                                  unsigned short* __restrict__ T) {
  extern __shared__ char smem[];  // 3 x (16 KB x + 16 KB Wvt)
  const int t = threadIdx.x, lane = t & 63, w = t >> 6;
  const int wm = w >> 1, wn = w & 1;
  const int l15 = lane & 15, l4 = lane >> 4;
  const int m0 = blockIdx.x * 64;

  // staging addresses (pre-swizzled source per rule #21; LDS dest linear per-wave)
  int xrow_[2], xsrc_[2];
#pragma unroll
  for (int c = 0; c < 2; ++c) {
    xrow_[c] = c * 32 + (t >> 4);                 // 0..63
    xsrc_[c] = ((t & 15) << 4) ^ ((xrow_[c] & 7) << 4);
  }
  int wrow_[2], wsrc_[2];
#pragma unroll
  for (int c = 0; c < 2; ++c) {
    wrow_[c] = c * 64 + (t >> 3);                 // 0..127
    wsrc_[c] = ((t & 7) << 4) ^ ((wrow_[c] & 7) << 4);
  }

  f32x4 acc[4];
#pragma unroll
  for (int ni = 0; ni < 4; ++ni)
#pragma unroll
    for (int r = 0; r < 4; ++r) acc[ni][r] = 0.f;

#define VMCNT(n) asm volatile("s_waitcnt vmcnt(" #n ")" ::: "memory")
#define BAR() __builtin_amdgcn_s_barrier()
#define SCHED0() __builtin_amdgcn_sched_barrier(0)

#define STAGE(tt, buf)                                                         \
  do {                                                                         \
    _Pragma("unroll") for (int c = 0; c < 2; ++c)                              \
        gload16((const char*)(X + (size_t)(m0 + xrow_[c]) * 2048) +            \
                    (tt) * 256 + xsrc_[c],                                     \
                smem + (buf) * 32768 + c * 8192 + w * 1024);                   \
    _Pragma("unroll") for (int c = 0; c < 2; ++c)                              \
        gload16((const char*)Wvt + (size_t)wrow_[c] * 4096 + (tt) * 128 +      \
                    wsrc_[c],                                                  \
                smem + (buf) * 32768 + 16384 + c * 8192 + w * 1024);           \
  } while (0)

#define COMPUTE(buf)                                                           \
  do {                                                                         \
    const char* xs = smem + (buf) * 32768;                                     \
    const char* ws = smem + (buf) * 32768 + 16384;                             \
    const int arow = wm * 16 + l15;                                            \
    const char* xr = xs + arow * 256;                                          \
    const int aswz = (arow & 7) << 4;                                          \
    bf16x8 af[2];                                                              \
    _Pragma("unroll") for (int ks = 0; ks < 2; ++ks) {                         \
      f32x4 a0 = *(const f32x4*)(xr + ((ks * 128 + l4 * 32) ^ aswz));          \
      f32x4 a1 = *(const f32x4*)(xr + ((ks * 128 + l4 * 32 + 16) ^ aswz));     \
      u16x8 u;                                                                 \
      _Pragma("unroll") for (int jj = 0; jj < 4; ++jj) {                       \
        u[jj] = f2bf(a0[jj]); u[jj + 4] = f2bf(a1[jj]);                        \
      }                                                                        \
      af[ks] = (bf16x8)u;                                                      \
    }                                                                          \
    _Pragma("unroll") for (int ni = 0; ni < 4; ++ni) {                         \
      const int brow = wn * 64 + ni * 16 + l15;                                \
      const int bswz = (brow & 7) << 4;                                        \
      _Pragma("unroll") for (int ks = 0; ks < 2; ++ks) {                       \
        bf16x8 bf = *(const bf16x8*)(ws + brow * 128 +                         \
                                     ((ks * 64 + l4 * 16) ^ bswz));            \
        acc[ni] = __builtin_amdgcn_mfma_f32_16x16x32_bf16(af[ks], bf,          \
                                                          acc[ni], 0, 0, 0);   \
      }                                                                        \
    }                                                                          \
  } while (0)

#define TILE(tt, bR, bS)                                                       \
  STAGE((tt) + 2, bS); VMCNT(8); BAR(); SCHED0();                              \
  COMPUTE(bR); SCHED0(); BAR();

  STAGE(0, 0);
  STAGE(1, 1);

#pragma unroll 1
  for (int it = 0; it < 10; ++it) {
    const int tb = it * 3;
    TILE(tb + 0, 0, 2)
    TILE(tb + 1, 1, 0)
    TILE(tb + 2, 2, 1)
  }
  // peeled tail: tiles 30 (buf0), 31 (buf1); no more staging
  VMCNT(4); BAR(); SCHED0(); COMPUTE(0); SCHED0(); BAR();
  VMCNT(0); BAR(); SCHED0(); COMPUTE(1);

#undef TILE
#undef COMPUTE
#undef STAGE
#undef VMCNT
#undef BAR
#undef SCHED0

#pragma unroll
  for (int ni = 0; ni < 4; ++ni)
#pragma unroll
    for (int r = 0; r < 4; ++r) {
      int row = m0 + wm * 16 + l4 * 4 + r;
      int col = wn * 64 + ni * 16 + l15;
      T[(size_t)row * 128 + col] = f2bf(acc[ni][r]);
    }
}

// ---- GEMM2: Y[16384][2048] fp32 = T * Wst^T + beff.  K=128 single sweep ----
// r12 version (proven): grid (256 m, 16 n), 4 blocks/CU, B-tile 32 KB one-shot stage.
__global__ __launch_bounds__(256, 4) void k_gemm2(const unsigned short* __restrict__ Tm,
                                                  const unsigned short* __restrict__ Wst,
                                                  const float* __restrict__ be,
                                                  float* __restrict__ Y) {
  __shared__ char bs[32768];
  const int t = threadIdx.x, lane = t & 63, w = t >> 6;
  const int l15 = lane & 15, l4 = lane >> 4;
  const int m0 = blockIdx.x * 64, n0 = blockIdx.y * 128;

#pragma unroll
  for (int c = 0; c < 8; ++c) {
    int row = c * 16 + (t >> 4);
    int sc = ((t & 15) * 16) ^ ((row & 7) << 4);
    gload16((const char*)Wst + (size_t)(n0 + row) * 256 + sc, bs + c * 4096 + w * 1024);
  }
  const unsigned short* trow = Tm + (size_t)(m0 + w * 16 + l15) * 128;
  bf16x8 afr[4];
#pragma unroll
  for (int kq = 0; kq < 4; ++kq) afr[kq] = *(const bf16x8*)(trow + kq * 32 + l4 * 8);
  __syncthreads();

  f32x4 acc[8];
#pragma unroll
  for (int nf = 0; nf < 8; ++nf)
#pragma unroll
    for (int r = 0; r < 4; ++r) acc[nf][r] = 0.f;

#pragma unroll
  for (int nf = 0; nf < 8; ++nf) {
    int row = nf * 16 + l15;
#pragma unroll
    for (int kq = 0; kq < 4; ++kq) {
      int byt = (kq * 64 + l4 * 16) ^ ((row & 7) << 4);
      bf16x8 bf = *(const bf16x8*)(bs + row * 256 + byt);
      acc[nf] = __builtin_amdgcn_mfma_f32_16x16x32_bf16(afr[kq], bf, acc[nf], 0, 0, 0);
    }
  }

#pragma unroll
  for (int nf = 0; nf < 8; ++nf) {
    int n = n0 + nf * 16 + l15;
    float bv = be[n];
#pragma unroll
    for (int r = 0; r < 4; ++r) {
      int row = m0 + w * 16 + l4 * 4 + r;
      Y[(size_t)row * 2048 + n] = acc[nf][r] + bv;
    }
  }
}

extern "C" void kernel_launch(void* const* d_in, const int* in_sizes, int n_in,
                              void* d_out, int out_size, void* d_ws, size_t ws_size,
                              hipStream_t stream) {
  const float* x    = (const float*)d_in[0];
  const float* Wqkv = (const float*)d_in[1];
  const float* bqkv = (const float*)d_in[2];
  const float* Wout = (const float*)d_in[3];
  const float* bout = (const float*)d_in[4];
  float* y = (float*)d_out;

  char* ws = (char*)d_ws;
  unsigned short* Wvt  = (unsigned short*)(ws);             //   524,288 B  [128][2048] bf16
  unsigned short* Wst  = (unsigned short*)(ws + 524288);    //   524,288 B  [2048][128] bf16
  float*          beff = (float*)(ws + 1048576);            //     8,192 B
  unsigned short* T    = (unsigned short*)(ws + 1056768);   // 4,194,304 B  [16384][128] bf16

  k_prep<<<2048, 256, 0, stream>>>(Wqkv, Wout, Wvt, Wst);
  k_beff<<<8, 256, 0, stream>>>(bqkv, Wst, bout, beff);
  k_gemm1<<<256, 512, 98304, stream>>>(x, Wvt, T);
  k_gemm2<<<dim3(256, 16), 256, 0, stream>>>(T, Wst, beff, y);
}